// Round 14
// baseline (553.368 us; speedup 1.0000x reference)
//
#include <hip/hip_runtime.h>
#include <hip/hip_bf16.h>
#include <hip/hip_fp16.h>

// DynamicSequenceChunker: B=8, L=4096, D=1024, DK=1024
// R14: R13 (passing, 551us; gemm_cos 205us) + ONE change: gemm2 processes
//      TWO K-steps per barrier (BK=64): 48 iters instead of 96, 3x32KB bufs
//      (each = two verbatim 16KB sub-steps), vmcnt(8) + 1 barrier per iter.
//      gemm2 runs ~112 blocks (<1/CU) so there is no occupancy to lose —
//      pure latency-chain halving (R11's transform, in the regime where it
//      pays). Slab boundaries (kk=32,64) are even => pairs never straddle.
//      Also fixup3b grid 8->32. All else byte-identical to R13.

#define B_ 8
#define L_ 4096
#define D_ 1024
#define M_TOT (B_ * L_)                 // 32768
#define BM 128
#define DS_ELEMS ((size_t)M_TOT * D_)   // 33554432
#define SUS_CAP 2048

typedef _Float16 f16x8 __attribute__((ext_vector_type(8)));
typedef _Float16 f16x4 __attribute__((ext_vector_type(4)));
typedef __bf16  bf16x8 __attribute__((ext_vector_type(8)));
typedef __bf16  bf16x4 __attribute__((ext_vector_type(4)));
typedef float   f32x4  __attribute__((ext_vector_type(4)));

typedef __attribute__((address_space(1))) void gv_t;
typedef __attribute__((address_space(3))) void lv_t;

__device__ __forceinline__ void gl_lds16(const void* g, void* l) {
    __builtin_amdgcn_global_load_lds((gv_t*)g, (lv_t*)l, 16, 0, 0);
}

// ---------------------------------------------------------------------------
// prep: tokens->fp16, W->wT fp16 + wT bf16 hi/lo, zero accumulators+counters
// ---------------------------------------------------------------------------
__global__ __launch_bounds__(256)
void prep(const float* __restrict__ tokens, const float* __restrict__ W,
          _Float16* __restrict__ t_h, _Float16* __restrict__ wT_h,
          __bf16* __restrict__ wT_hi, __bf16* __restrict__ wT_lo,
          float* __restrict__ zbase, float* __restrict__ aux_out)
{
    const int bid = blockIdx.x, tid = threadIdx.x;
    if (bid < 8192) {
        const size_t base = (size_t)bid * 4096 + tid * 4;
        #pragma unroll
        for (int r = 0; r < 4; ++r) {
            size_t idx = base + (size_t)r * 1024;
            float4 v = *(const float4*)&tokens[idx];
            f16x4 h;
            h[0] = (_Float16)v.x; h[1] = (_Float16)v.y;
            h[2] = (_Float16)v.z; h[3] = (_Float16)v.w;
            *(f16x4*)&t_h[idx] = h;
        }
    } else if (bid < 10240) {
        __shared__ float lw[32 * 33];
        const int local = bid - 8192;
        const int k0 = (local & 31) * 32;
        const int n0 = (local >> 5) * 32;
        {
            const int lk = tid >> 3, ln4 = (tid & 7) * 4;
            float4 v = *(const float4*)&W[(size_t)(k0 + lk) * 2048 + n0 + ln4];
            lw[(ln4 + 0) * 33 + lk] = v.x;
            lw[(ln4 + 1) * 33 + lk] = v.y;
            lw[(ln4 + 2) * 33 + lk] = v.z;
            lw[(ln4 + 3) * 33 + lk] = v.w;
        }
        __syncthreads();
        {
            const int ln = tid >> 3, lk4 = (tid & 7) * 4;
            f16x4 h; bf16x4 bh, bl;
            #pragma unroll
            for (int j = 0; j < 4; ++j) {
                float v = lw[ln * 33 + lk4 + j];
                h[j] = (_Float16)v;
                __bf16 b = (__bf16)v;
                bh[j] = b;
                bl[j] = (__bf16)(v - (float)b);
            }
            size_t o = (size_t)(n0 + ln) * 1024 + k0 + lk4;
            *(f16x4*)&wT_h[o]   = h;
            *(bf16x4*)&wT_hi[o] = bh;
            *(bf16x4*)&wT_lo[o] = bl;
        }
    } else {
        const int zb = bid - 10240;                // 0..96
        const int i = zb * 1024 + tid * 4;
        if (i < 98308)
            *(float4*)&zbase[i] = make_float4(0.f, 0.f, 0.f, 0.f);
        if (zb == 0 && tid == 0) *aux_out = 0.f;
    }
}

// ---------------------------------------------------------------------------
// main GEMM: fp16, tile 256 rows x (128 q-cols + 128 k-cols), 512 threads
// [R13 verbatim] grid 1024, 8 waves, A 3x16KB prefetch-2, B 2x16KB
// prefetch-1, vmcnt(2) + 1 barrier. Ck overlay [256][130] = 133120 B.
// ---------------------------------------------------------------------------
__global__ __launch_bounds__(512, 2)
void gemm_cos_f16(const _Float16* __restrict__ t_h, const _Float16* __restrict__ wT_h,
                  float* __restrict__ dotw, float* __restrict__ qn2w,
                  float* __restrict__ ksn2w,
                  float* __restrict__ qrow, float* __restrict__ krow)
{
    __shared__ float smem[33280];       // 133120 B (Ck overlay size)
    float* Ck = smem;                   // [256][130]

    const int bx = blockIdx.x;          // 0..1023
    const int tile_n = (bx >> 3) & 7;
    const int tile_m = ((bx >> 6) & 15) + ((bx & 7) << 4);   // 0..127
    const int m0 = tile_m * 256;
    const int n0 = tile_n * 128;
    const int tid  = threadIdx.x;       // 0..511
    const int w    = tid >> 6;          // 0..7
    const int lane = tid & 63;
    const int quad = lane >> 4;
    const int lc   = lane & 15;

    const int wm  = (w & 3) * 64;       // row quarter (0/64/128/192)
    const int wq0 = (w >> 2) * 64;      // col half (0/64) within 128

    const int st_ch = ((lane & 3) ^ ((lane >> 3) & 3)) * 8;
    const int ia0 = w * 2, ia1 = w * 2 + 1;
    const size_t a_g0 = (size_t)(m0 + ia0 * 16 + (lane >> 2)) * 1024 + st_ch;
    const size_t a_g1 = a_g0 + (size_t)16 * 1024;
    size_t b_g[2];
    #pragma unroll
    for (int j = 0; j < 2; ++j) {
        const int br = (w * 2 + j) * 16 + (lane >> 2);
        const int gr = (br < 128) ? (n0 + br) : (896 + n0 + br);
        b_g[j] = (size_t)gr * 1024 + st_ch;
    }

    char* const sb  = (char*)smem;      // A bufs: 0 / 16384 / 32768
    char* const sbB = sb + 49152;       // B bufs: 49152 / 65536 (16KB each)
    const int fr_ch = (quad ^ ((lc >> 1) & 3)) * 8;

    f32x4 accq[4][4] = {};
    f32x4 acck[4][4] = {};

#define STAGE_A(KK, BASE)                                                    \
    {                                                                        \
        const size_t kb = (size_t)(KK) * 32;                                 \
        gl_lds16(t_h + a_g0 + kb, (BASE) + ia0 * 1024);                      \
        gl_lds16(t_h + a_g1 + kb, (BASE) + ia1 * 1024);                      \
    }
#define STAGE_B(KK, BASE)                                                    \
    {                                                                        \
        const size_t kb = (size_t)(KK) * 32;                                 \
        gl_lds16(wT_h + b_g[0] + kb, (BASE) + (w * 2 + 0) * 1024);           \
        gl_lds16(wT_h + b_g[1] + kb, (BASE) + (w * 2 + 1) * 1024);           \
    }

    // prologue (issue order defines vm queue): A(0), B(0), A(1)
    STAGE_A(0, sb)
    STAGE_B(0, sbB)
    STAGE_A(1, sb + 16384)

    int acur = 0;
    int apre = 2;
    for (int kk = 0; kk < 32; ++kk) {
        if (kk < 31) {
            asm volatile("s_waitcnt vmcnt(2)" ::: "memory");
        } else {
            asm volatile("s_waitcnt vmcnt(0)" ::: "memory");
        }
        __builtin_amdgcn_s_barrier();
        if (kk < 31) STAGE_B(kk + 1, sbB + ((kk + 1) & 1) * 16384)
        if (kk < 30) STAGE_A(kk + 2, sb + apre * 16384)

        const _Float16* As = (const _Float16*)(sb + acur * 16384);
        const _Float16* Bs = (const _Float16*)(sbB + (kk & 1) * 16384);

        f16x8 af[4], bq[4], bk[4];
        #pragma unroll
        for (int mi = 0; mi < 4; ++mi)
            af[mi] = *(const f16x8*)(As + (wm + mi * 16 + lc) * 32 + fr_ch);
        #pragma unroll
        for (int ni = 0; ni < 4; ++ni) {
            bq[ni] = *(const f16x8*)(Bs + (wq0 + ni * 16 + lc) * 32 + fr_ch);
            bk[ni] = *(const f16x8*)(Bs + (128 + wq0 + ni * 16 + lc) * 32 + fr_ch);
        }
        #pragma unroll
        for (int mi = 0; mi < 4; ++mi) {
            #pragma unroll
            for (int ni = 0; ni < 4; ++ni) {
                accq[mi][ni] = __builtin_amdgcn_mfma_f32_16x16x32_f16(
                    af[mi], bq[ni], accq[mi][ni], 0, 0, 0);
                acck[mi][ni] = __builtin_amdgcn_mfma_f32_16x16x32_f16(
                    af[mi], bk[ni], acck[mi][ni], 0, 0, 0);
            }
        }
        acur = (acur == 2) ? 0 : acur + 1;
        apre = (apre == 2) ? 0 : apre + 1;
    }
#undef STAGE_A
#undef STAGE_B
    __syncthreads();   // all staging settled before the Ck overlay

    // ---- epilogue (rows 0..255, Ck stride 130) ----
    #pragma unroll
    for (int mi = 0; mi < 4; ++mi) {
        #pragma unroll
        for (int reg = 0; reg < 4; ++reg) {
            const int row = wm + mi * 16 + quad * 4 + reg;   // 0..255
            float s = 0.f, s2 = 0.f;
            #pragma unroll
            for (int ni = 0; ni < 4; ++ni) {
                s  += accq[mi][ni][reg] * accq[mi][ni][reg];
                s2 += acck[mi][ni][reg] * acck[mi][ni][reg];
            }
            s += __shfl_xor(s, 1); s += __shfl_xor(s, 2);
            s += __shfl_xor(s, 4); s += __shfl_xor(s, 8);
            if (lc == 0) atomicAdd(&qn2w[m0 + row], s);

            s2 += __shfl_xor(s2, 1); s2 += __shfl_xor(s2, 2);
            s2 += __shfl_xor(s2, 4); s2 += __shfl_xor(s2, 8);
            if (lc == 0 && row < 255) atomicAdd(&ksn2w[m0 + row + 1], s2);
        }
    }

    #pragma unroll
    for (int mi = 0; mi < 4; ++mi)
        #pragma unroll
        for (int ni = 0; ni < 4; ++ni)
            #pragma unroll
            for (int reg = 0; reg < 4; ++reg)
                Ck[(wm + mi * 16 + quad * 4 + reg) * 130 + wq0 + ni * 16 + lc] =
                    acck[mi][ni][reg];
    __syncthreads();

    #pragma unroll
    for (int mi = 0; mi < 4; ++mi) {
        #pragma unroll
        for (int reg = 0; reg < 4; ++reg) {
            const int row = wm + mi * 16 + quad * 4 + reg;
            float d = 0.f;
            if (row >= 1) {
                #pragma unroll
                for (int ni = 0; ni < 4; ++ni)
                    d += accq[mi][ni][reg]
                       * Ck[(row - 1) * 130 + wq0 + ni * 16 + lc];
            }
            d += __shfl_xor(d, 1); d += __shfl_xor(d, 2);
            d += __shfl_xor(d, 4); d += __shfl_xor(d, 8);
            if (lc == 0 && row >= 1) atomicAdd(&dotw[m0 + row], d);
        }
    }

    // boundary rows for probs_fused (128-row tiles)
    if (wm == 0 && quad == 0) {
        #pragma unroll
        for (int ni = 0; ni < 4; ++ni)
            qrow[(size_t)(tile_m * 2) * D_ + n0 + wq0 + ni * 16 + lc] =
                accq[0][ni][0];
    }
    if (wm == 128 && quad == 0) {
        #pragma unroll
        for (int ni = 0; ni < 4; ++ni)
            qrow[(size_t)(tile_m * 2 + 1) * D_ + n0 + wq0 + ni * 16 + lc] =
                accq[0][ni][0];
    }
    if (wm == 64 && quad == 3) {
        #pragma unroll
        for (int ni = 0; ni < 4; ++ni)
            krow[(size_t)(tile_m * 2) * D_ + n0 + wq0 + ni * 16 + lc] =
                acck[3][ni][3];
    }
    if (wm == 192 && quad == 3) {
        #pragma unroll
        for (int ni = 0; ni < 4; ++ni)
            krow[(size_t)(tile_m * 2 + 1) * D_ + n0 + wq0 + ni * 16 + lc] =
                acck[3][ni][3];
    }
}

// ---------------------------------------------------------------------------
// fused: boundary dot (t ≡ 0 mod 128) + probs + suspect list (|cos| < 1e-3)
// ---------------------------------------------------------------------------
__global__ __launch_bounds__(256)
void probs_fused(const float* __restrict__ qrow, const float* __restrict__ krow,
                 const float* __restrict__ start_key,
                 const float* __restrict__ dotw, const float* __restrict__ qn2w,
                 const float* __restrict__ ksn2w, float* __restrict__ probsw,
                 int* __restrict__ scount, int* __restrict__ slist)
{
    const int tile = blockIdx.x;
    const int tid = threadIdx.x;
    __shared__ float sd[4], sk[4];

    {
        const float* q  = qrow + (size_t)tile * D_;
        const float* ks = ((tile & 31) == 0) ? start_key
                                             : (krow + (size_t)(tile - 1) * D_);
        float4 qv = *(const float4*)&q[tid * 4];
        float4 kv = *(const float4*)&ks[tid * 4];
        float d  = qv.x * kv.x + qv.y * kv.y + qv.z * kv.z + qv.w * kv.w;
        float k2 = kv.x * kv.x + kv.y * kv.y + kv.z * kv.z + kv.w * kv.w;
        #pragma unroll
        for (int off = 32; off; off >>= 1) {
            d  += __shfl_down(d, off, 64);
            k2 += __shfl_down(k2, off, 64);
        }
        const int lane = tid & 63, wid = tid >> 6;
        if (lane == 0) { sd[wid] = d; sk[wid] = k2; }
    }
    __syncthreads();

    if (tid < BM) {
        const int m = tile * BM + tid;
        float dd = dotw[m], kk = ksn2w[m];
        if (tid == 0) {
            dd = sd[0] + sd[1] + sd[2] + sd[3];
            kk = sk[0] + sk[1] + sk[2] + sk[3];
        }
        float qn = fmaxf(sqrtf(qn2w[m]), 1e-8f);
        float kn = fmaxf(sqrtf(kk), 1e-8f);
        float c = dd / (qn * kn);
        probsw[m] = 0.5f * (1.f - c);
        if (fabsf(c) < 1e-3f) {
            int i = atomicAdd(scount, 1);
            if (i < SUS_CAP) slist[i] = m;
        }
    }
}

// ---------------------------------------------------------------------------
// stage-2 operand build: gather suspect rows (and predecessors) -> bf16 hi/lo
// ---------------------------------------------------------------------------
__global__ __launch_bounds__(256)
void gather_split(const float* __restrict__ tokens, const int* __restrict__ scount,
                  const int* __restrict__ slist,
                  __bf16* __restrict__ As_hi, __bf16* __restrict__ As_lo)
{
    int n = *scount; if (n > SUS_CAP) n = SUS_CAP;
    const int n_up = (n + 127) & ~127;
    const int slot = blockIdx.x;
    const int sl = slot & 2047;
    if (sl >= n_up) return;
    const int tid = threadIdx.x;

    int src = -1;
    if (sl < n) {
        int t = slist[sl];
        if (slot < 2048) src = t;
        else src = ((t & 4095) == 0) ? t : (t - 1);
    }
    bf16x4 h = {}, l = {};
    if (src >= 0) {
        float4 v = *(const float4*)&tokens[(size_t)src * 1024 + tid * 4];
        float vs[4] = {v.x, v.y, v.z, v.w};
        #pragma unroll
        for (int j = 0; j < 4; ++j) {
            __bf16 b = (__bf16)vs[j];
            h[j] = b;
            l[j] = (__bf16)(vs[j] - (float)b);
        }
    }
    size_t o = (size_t)slot * 1024 + tid * 4;
    *(bf16x4*)&As_hi[o] = h;
    *(bf16x4*)&As_lo[o] = l;
}

// ---------------------------------------------------------------------------
// stage-2 GEMM: bf16 3-slab on gathered rows, writes C2 fp32
// R14: BK=64 — two verbatim 16KB sub-steps per barrier. 48 iters (was 96),
//      3 bufs x 32KB @ 0/32768/65536, prefetch-2 pairs, vmcnt(8) + 1 barrier.
//      Pair p covers kk = 2p, 2p+1; slab = p>>4 (pairs never straddle slabs).
//      suspect blocks (tm<16): q-cols only; predecessor blocks: k-cols only.
// ---------------------------------------------------------------------------
__global__ __launch_bounds__(256, 1)
void gemm2(const __bf16* __restrict__ As_hi, const __bf16* __restrict__ As_lo,
           const __bf16* __restrict__ wT_hi, const __bf16* __restrict__ wT_lo,
           const int* __restrict__ scount, float* __restrict__ C2)
{
    int n = *scount; if (n > SUS_CAP) n = SUS_CAP;
    const int tm = blockIdx.y;
    const int local_base = (tm < 16) ? tm * 128 : (tm - 16) * 128;
    if (local_base >= n) return;
    const int m0 = (tm < 16) ? tm * 128 : 2048 + (tm - 16) * 128;

    __shared__ float smem[24576];       // 98304 B = 3 bufs x 32 KB

    const int tile_n = blockIdx.x;      // 0..7
    const int n0 = tile_n * 128;
    const int colbase = ((tm < 16) ? 0 : 1024) + n0;
    const int tid  = threadIdx.x;
    const int w    = tid >> 6;
    const int lane = tid & 63;
    const int quad = lane >> 4;
    const int lc   = lane & 15;
    const int wm  = (w & 1) * 64;
    const int wq0 = (w >> 1) * 32;

    const int ia0 = w * 2, ia1 = w * 2 + 1;
    const int st_ch = ((lane & 3) ^ ((lane >> 3) & 3)) * 8;
    const size_t a_g0 = (size_t)(m0 + ia0 * 16 + (lane >> 2)) * 1024 + st_ch;
    const size_t a_g1 = a_g0 + (size_t)16 * 1024;
    const int br0 = ia0 * 16 + (lane >> 2);
    const int br1 = br0 + 16;
    const size_t b_g0 = (size_t)(colbase + br0) * 1024 + st_ch;
    const size_t b_g1 = (size_t)(colbase + br1) * 1024 + st_ch;

    char* const sb = (char*)smem;
    const int fr_ch = (quad ^ ((lc >> 1) & 3)) * 8;

    f32x4 accq[4][2] = {};
    f32x4 acck[4][2] = {};

    // Pair p: kk0 = 2p (kb (p&15)*64), kk1 = 2p+1 (kb +32); slab = p>>4.
    // Sub-step h at BASE + h*16384: [A 8K | B 8K] verbatim layout.
#define STAGE_PAIR(P, BASE)                                                  \
    {                                                                        \
        const int slab = (P) >> 4;                                           \
        const __bf16* Ap = (slab < 2) ? As_hi : As_lo;                       \
        const __bf16* Bp = (slab == 1) ? wT_lo : wT_hi;                      \
        const size_t kb = (size_t)((P) & 15) * 64;                           \
        gl_lds16(Ap + a_g0 + kb,      (BASE) + ia0 * 1024);                  \
        gl_lds16(Ap + a_g1 + kb,      (BASE) + ia1 * 1024);                  \
        gl_lds16(Bp + b_g0 + kb,      (BASE) + 8192 + ia0 * 1024);           \
        gl_lds16(Bp + b_g1 + kb,      (BASE) + 8192 + ia1 * 1024);           \
        gl_lds16(Ap + a_g0 + kb + 32, (BASE) + 16384 + ia0 * 1024);          \
        gl_lds16(Ap + a_g1 + kb + 32, (BASE) + 16384 + ia1 * 1024);          \
        gl_lds16(Bp + b_g0 + kb + 32, (BASE) + 16384 + 8192 + ia0 * 1024);   \
        gl_lds16(Bp + b_g1 + kb + 32, (BASE) + 16384 + 8192 + ia1 * 1024);   \
    }

    // prologue: pair 0 -> buf0, pair 1 -> buf1 (16 loads/wave in flight)
    STAGE_PAIR(0, sb)
    STAGE_PAIR(1, sb + 32768)

    int cur = 0;                        // buf holding pair p   (= p % 3)
    for (int p = 0; p < 48; ++p) {
        // drain pair p's 8 loads; keep pair p+1's 8 in flight
        if (p < 47) {
            asm volatile("s_waitcnt vmcnt(8)" ::: "memory");
        } else {
            asm volatile("s_waitcnt vmcnt(0)" ::: "memory");
        }
        __builtin_amdgcn_s_barrier();
        if (p < 46) {
            int nxt = cur + 2; if (nxt >= 3) nxt -= 3;
            STAGE_PAIR(p + 2, sb + nxt * 32768)
        }
        const char* Pb = sb + cur * 32768;
        #pragma unroll
        for (int h = 0; h < 2; ++h) {
            const __bf16* As = (const __bf16*)(Pb + h * 16384);
            const __bf16* Bs = As + 4096;

            bf16x8 af[4], bq[2], bk[2];
            #pragma unroll
            for (int mi = 0; mi < 4; ++mi)
                af[mi] = *(const bf16x8*)(As + (wm + mi * 16 + lc) * 32 + fr_ch);
            #pragma unroll
            for (int ni = 0; ni < 2; ++ni) {
                bq[ni] = *(const bf16x8*)(Bs + (wq0 + ni * 16 + lc) * 32 + fr_ch);
                bk[ni] = *(const bf16x8*)(Bs + (64 + wq0 + ni * 16 + lc) * 32 + fr_ch);
            }
            #pragma unroll
            for (int mi = 0; mi < 4; ++mi) {
                #pragma unroll
                for (int ni = 0; ni < 2; ++ni) {
                    accq[mi][ni] = __builtin_amdgcn_mfma_f32_16x16x32_bf16(
                        af[mi], bq[ni], accq[mi][ni], 0, 0, 0);
                    acck[mi][ni] = __builtin_amdgcn_mfma_f32_16x16x32_bf16(
                        af[mi], bk[ni], acck[mi][ni], 0, 0, 0);
                }
            }
        }
        cur = (cur == 2) ? 0 : cur + 1;
    }
#undef STAGE_PAIR

    #pragma unroll
    for (int mi = 0; mi < 4; ++mi) {
        #pragma unroll
        for (int reg = 0; reg < 4; ++reg) {
            const int row = m0 + wm + mi * 16 + quad * 4 + reg;
            #pragma unroll
            for (int ni = 0; ni < 2; ++ni) {
                C2[(size_t)row * 2048 + colbase + wq0 + ni * 16 + lc] = accq[mi][ni][reg];
                C2[(size_t)row * 2048 + colbase + 64 + wq0 + ni * 16 + lc] = acck[mi][ni][reg];
            }
        }
    }
}

// ---------------------------------------------------------------------------
// stage-2 resolve: dot/norms from C2; sub-suspects (|cos|<1e-4) -> slist2
// on append, zero the suspect's 3-float fix3acc slot.
// ---------------------------------------------------------------------------
__global__ __launch_bounds__(256)
void dot_fix(const float* __restrict__ C2, const float* __restrict__ start_key,
             const int* __restrict__ scount, const int* __restrict__ slist,
             float* __restrict__ probsw, int* __restrict__ scount2,
             int* __restrict__ slist2, float* __restrict__ fix3acc)
{
    int n = *scount; if (n > SUS_CAP) n = SUS_CAP;
    const int s = blockIdx.x;
    if (s >= n) return;
    const int tid = threadIdx.x;
    const int t = slist[s];
    const bool st = (t & 4095) == 0;
    const float* q = C2 + (size_t)s * 2048;
    const float* k = st ? start_key : (C2 + (size_t)(2048 + s) * 2048 + 1024);

    float4 qv = *(const float4*)&q[tid * 4];
    float4 kv = *(const float4*)&k[tid * 4];
    float d  = qv.x * kv.x + qv.y * kv.y + qv.z * kv.z + qv.w * kv.w;
    float q2 = qv.x * qv.x + qv.y * qv.y + qv.z * qv.z + qv.w * qv.w;
    float k2 = kv.x * kv.x + kv.y * kv.y + kv.z * kv.z + kv.w * kv.w;
    #pragma unroll
    for (int off = 32; off; off >>= 1) {
        d  += __shfl_down(d, off, 64);
        q2 += __shfl_down(q2, off, 64);
        k2 += __shfl_down(k2, off, 64);
    }
    __shared__ float sd[4], sq[4], sk[4];
    const int lane = tid & 63, wid = tid >> 6;
    if (lane == 0) { sd[wid] = d; sq[wid] = q2; sk[wid] = k2; }
    __syncthreads();
    if (tid == 0) {
        float D  = sd[0] + sd[1] + sd[2] + sd[3];
        float Q2 = sq[0] + sq[1] + sq[2] + sq[3];
        float K2 = sk[0] + sk[1] + sk[2] + sk[3];
        float c = D / (fmaxf(sqrtf(Q2), 1e-8f) * fmaxf(sqrtf(K2), 1e-8f));
        if (fabsf(c) < 1e-4f) {
            int i = atomicAdd(scount2, 1);
            if (i < SUS_CAP) {
                slist2[i] = t;
                float* fa = fix3acc + 3 * i;
                fa[0] = 0.f; fa[1] = 0.f; fa[2] = 0.f;
            }
        } else {
            probsw[t] = 0.5f * (1.f - c);
        }
    }
}

// ---------------------------------------------------------------------------
// stage-3a: exact fp32 recompute, split over OUTPUT cols.  [R10 verbatim]
// ---------------------------------------------------------------------------
__global__ __launch_bounds__(256)
void fixup3a(const float* __restrict__ tokens, const float* __restrict__ W,
             const float* __restrict__ start_key, const int* __restrict__ scount2,
             const int* __restrict__ slist2, float* __restrict__ fix3acc)
{
    __shared__ float ta[1024], tb[1024], kvs[128];
    const int tid = threadIdx.x;
    const int lane = tid & 63;
    const int c = blockIdx.x & 7;
    int n = *scount2; if (n > SUS_CAP) n = SUS_CAP;

    for (int i = blockIdx.x >> 3; i < n; i += 128) {
        const int t = slist2[i];
        const bool st = (t & 4095) == 0;
        *(float4*)&ta[tid * 4] = *(const float4*)&tokens[(size_t)t * 1024 + tid * 4];
        if (!st)
            *(float4*)&tb[tid * 4] = *(const float4*)&tokens[(size_t)(t - 1) * 1024 + tid * 4];
        __syncthreads();

        float qd = 0.f, q2p = 0.f, k2p = 0.f, dotp = 0.f;
        if (tid < 128) {
            const float* Wp = W + c * 128 + tid;
            float a0 = 0.f, a1 = 0.f, a2 = 0.f, a3 = 0.f;
            for (int k = 0; k < 1024; k += 4) {
                a0 = fmaf(ta[k + 0], Wp[(size_t)(k + 0) * 2048], a0);
                a1 = fmaf(ta[k + 1], Wp[(size_t)(k + 1) * 2048], a1);
                a2 = fmaf(ta[k + 2], Wp[(size_t)(k + 2) * 2048], a2);
                a3 = fmaf(ta[k + 3], Wp[(size_t)(k + 3) * 2048], a3);
            }
            qd = (a0 + a1) + (a2 + a3);
            q2p = qd * qd;
        } else {
            const int j = tid - 128;
            float kd;
            if (st) {
                kd = start_key[c * 128 + j];
            } else {
                const float* Wp = W + 1024 + c * 128 + j;
                float a0 = 0.f, a1 = 0.f, a2 = 0.f, a3 = 0.f;
                for (int k = 0; k < 1024; k += 4) {
                    a0 = fmaf(tb[k + 0], Wp[(size_t)(k + 0) * 2048], a0);
                    a1 = fmaf(tb[k + 1], Wp[(size_t)(k + 1) * 2048], a1);
                    a2 = fmaf(tb[k + 2], Wp[(size_t)(k + 2) * 2048], a2);
                    a3 = fmaf(tb[k + 3], Wp[(size_t)(k + 3) * 2048], a3);
                }
                kd = (a0 + a1) + (a2 + a3);
            }
            kvs[j] = kd;
            k2p = kd * kd;
        }
        __syncthreads();
        if (tid < 128) dotp = qd * kvs[tid];

        #pragma unroll
        for (int off = 32; off; off >>= 1) {
            dotp += __shfl_down(dotp, off, 64);
            q2p  += __shfl_down(q2p,  off, 64);
            k2p  += __shfl_down(k2p,  off, 64);
        }
        if (lane == 0) {
            float* fa = fix3acc + 3 * i;
            atomicAdd(&fa[0], dotp);
            atomicAdd(&fa[1], q2p);
            atomicAdd(&fa[2], k2p);
        }
        __syncthreads();   // protect ta/tb/kvs before next iteration
    }
}

// ---------------------------------------------------------------------------
// stage-3b: finish probs from accumulated {dot, q2, k2}
// ---------------------------------------------------------------------------
__global__ __launch_bounds__(256)
void fixup3b(const int* __restrict__ scount2, const int* __restrict__ slist2,
             const float* __restrict__ fix3acc, float* __restrict__ probsw)
{
    int n = *scount2; if (n > SUS_CAP) n = SUS_CAP;
    for (int i = threadIdx.x + blockIdx.x * 256; i < n; i += 256 * gridDim.x) {
        const int t = slist2[i];
        const float* fa = fix3acc + 3 * i;
        float D = fa[0], Q2 = fa[1], K2 = fa[2];
        float qn = fmaxf(sqrtf(Q2), 1e-8f), kn = fmaxf(sqrtf(K2), 1e-8f);
        probsw[t] = 0.5f * (1.f - D / (qn * kn));
    }
}

// ---------------------------------------------------------------------------
__global__ __launch_bounds__(1024)
void chunk_scan_p(const float* __restrict__ probsw, int* __restrict__ bposw,
                  int* __restrict__ ncw, float* __restrict__ aux_out,
                  float* __restrict__ out_lens)
{
    const int b = blockIdx.x, tid = threadIdx.x;
    const int lane = tid & 63, wid = tid >> 6;
    __shared__ int wcnt[16];
    __shared__ float wsum[16];
    __shared__ int s_nc;
    __shared__ float s_ps;

    const int base = b * L_ + tid * 4;
    float4 pv = *(const float4*)&probsw[base];
    const float p[4] = {pv.x, pv.y, pv.z, pv.w};

    bool mk[4]; int cnt = 0; float psum = 0.f;
    #pragma unroll
    for (int j = 0; j < 4; ++j) {
        mk[j] = (p[j] > 0.5f) || ((tid * 4 + j) == 0);
        cnt += mk[j] ? 1 : 0;
        psum += p[j];
    }
    int inc = cnt;
    #pragma unroll
    for (int off = 1; off < 64; off <<= 1) {
        int nn = __shfl_up(inc, off, 64);
        if (lane >= off) inc += nn;
    }
    float ps = psum;
    #pragma unroll
    for (int off = 32; off; off >>= 1) ps += __shfl_down(ps, off, 64);
    if (lane == 63) wcnt[wid] = inc;
    if (lane == 0)  wsum[wid] = ps;
    __syncthreads();
    if (tid == 0) {
        int run = 0; float tt = 0.f;
        for (int i = 0; i < 16; ++i) { int c = wcnt[i]; wcnt[i] = run; run += c; tt += wsum[i]; }
        s_nc = run; s_ps = tt;
    }
    __syncthreads();
    const int nc = s_nc;
    int idx = wcnt[wid] + (inc - cnt);
    #pragma unroll
    for (int j = 0; j < 4; ++j)
        if (mk[j]) { bposw[b * L_ + idx] = tid * 4 + j; ++idx; }
    if (tid == 0) {
        ncw[b] = nc;
        float G  = s_ps * (1.f / L_);
        float Fm = (float)nc * (1.f / L_);
        atomicAdd(aux_out, 0.0045f * (5.f * Fm * G + (1.f - Fm) * (1.f - G)));
    }
    __syncthreads();
    #pragma unroll
    for (int j = 0; j < 4; ++j) {
        int i = tid * 4 + j;
        float len = 0.f;
        if (i < nc) {
            int pi  = bposw[b * L_ + i];
            int nxt = (i + 1 < nc) ? bposw[b * L_ + i + 1] : L_;
            len = (float)(nxt - pi);
        }
        out_lens[b * L_ + i] = len;
    }
}

__global__ __launch_bounds__(256)
void gather_ds(const float* __restrict__ tokens, const float* __restrict__ probsw,
               const int* __restrict__ bposw, const int* __restrict__ ncw,
               float* __restrict__ out)
{
    const int row = blockIdx.x;
    const int b = row >> 12, i = row & 4095;
    const int nc = ncw[b];
    float4 v = make_float4(0.f, 0.f, 0.f, 0.f);
    if (i < nc) {
        const int t = bposw[b * L_ + i];
        const float pv = probsw[b * L_ + t];
        float4 tv = *(const float4*)&tokens[((size_t)(b << 12) + t) * D_ + threadIdx.x * 4];
        v = make_float4(tv.x * pv, tv.y * pv, tv.z * pv, tv.w * pv);
    }
    *(float4*)&out[(size_t)row * D_ + threadIdx.x * 4] = v;
}

// ===========================================================================
extern "C" void kernel_launch(void* const* d_in, const int* in_sizes, int n_in,
                              void* d_out, int out_size, void* d_ws, size_t ws_size,
                              hipStream_t stream)
{
    const float* tokens    = (const float*)d_in[0];
    const float* W_qk      = (const float*)d_in[1];
    const float* start_key = (const float*)d_in[2];
    float* out = (float*)d_out;
    float* lens_out = out + DS_ELEMS;
    float* aux_out  = out + DS_ELEMS + M_TOT;

    // ws layout (floats) — total 1740812 floats ≈ 6.96 MB
    float* wf = (float*)d_ws;
    float* dotw    = wf;                       // 32768
    float* qn2w    = wf + 32768;               // 32768
    float* ksn2w   = wf + 65536;               // 32768
    int*   scount  = (int*)(wf + 98304);       // 1
    int*   scount2 = (int*)(wf + 98305);       // 1 (+2 pad)
    float* probsw  = wf + 98308;               // 32768
    int*   bposw   = (int*)(wf + 131076);      // 32768
    int*   ncw     = (int*)(wf + 163844);      // 8
    int*   slist   = (int*)(wf + 163852);      // 2048
    int*   slist2  = (int*)(wf + 165900);      // 2048
    float* qrow    = wf + 167948;              // 262144
    float* krow    = wf + 430092;              // 262144
    _Float16* wT_h = (_Float16*)(wf + 692236); // 2097152 halves

    // d_out scratch (overwritten by gather_ds at the end)
    _Float16* t_h  = (_Float16*)out;                   // 33554432 halves
    __bf16* As_hi  = (__bf16*)(out + 16777216);        // 4096x1024
    __bf16* As_lo  = (__bf16*)(out + 18874368);
    float*  C2     = out + 20971520;                   // 4096x2048 fp32
    __bf16* wT_hi  = (__bf16*)(out + 29360128);        // 2048x1024
    __bf16* wT_lo  = (__bf16*)(out + 30408704);
    // fix3acc: 3 floats x SUS_CAP, reuses the As_lo region (dead after gemm2,
    // zeroed per-slot by dot_fix, consumed by fixup3a/b before gather_ds).
    float* fix3acc = out + 18874368;

    prep<<<10337, 256, 0, stream>>>(tokens, W_qk, t_h, wT_h, wT_hi, wT_lo,
                                    wf, aux_out);
    gemm_cos_f16<<<1024, 512, 0, stream>>>(t_h, wT_h, dotw, qn2w, ksn2w,
                                           qrow, krow);
    probs_fused<<<256, 256, 0, stream>>>(qrow, krow, start_key, dotw, qn2w,
                                         ksn2w, probsw, scount, slist);
    gather_split<<<4096, 256, 0, stream>>>(tokens, scount, slist, As_hi, As_lo);
    gemm2<<<dim3(8, 32), 256, 0, stream>>>(As_hi, As_lo, wT_hi, wT_lo,
                                           scount, C2);
    dot_fix<<<2048, 256, 0, stream>>>(C2, start_key, scount, slist, probsw,
                                      scount2, slist2, fix3acc);
    fixup3a<<<1024, 256, 0, stream>>>(tokens, W_qk, start_key, scount2, slist2,
                                      fix3acc);
    fixup3b<<<32, 256, 0, stream>>>(scount2, slist2, fix3acc, probsw);
    chunk_scan_p<<<B_, 1024, 0, stream>>>(probsw, bposw, ncw, aux_out, lens_out);
    gather_ds<<<M_TOT, 256, 0, stream>>>(tokens, probsw, bposw, ncw, out);
}

// Round 15
// 546.537 us; speedup vs baseline: 1.0125x; 1.0125x over previous
//
#include <hip/hip_runtime.h>
#include <hip/hip_bf16.h>
#include <hip/hip_fp16.h>

// DynamicSequenceChunker: B=8, L=4096, D=1024, DK=1024
// R15: R13 (best passing, 551us) + ONE change: gemm2 parallelized over its
//      3 independent K-slabs (hi*hi, hi*lo, lo*hi). grid (8,32,3); each
//      block runs R13's proven 32-iter 3x16KB prefetch-2 loop on a fixed
//      (Ap,Bp) pair and writes a disjoint C2 buffer (C2a = old location;
//      C2b/C2c live in t_h's region, dead after gemm_cos). dot_fix sums
//      the three slabs. Serial chain per block: 96 -> 32 barrier-iters.
//      R14's neutral BK=64 gemm2 reverted. fixup3b grid 32 kept.
//      All other kernels byte-identical to R13.

#define B_ 8
#define L_ 4096
#define D_ 1024
#define M_TOT (B_ * L_)                 // 32768
#define BM 128
#define DS_ELEMS ((size_t)M_TOT * D_)   // 33554432
#define SUS_CAP 2048

// C2 slab float-offsets within d_out
#define C2A_OFF 20971520u
#define C2B_OFF 0u
#define C2C_OFF 8388608u

typedef _Float16 f16x8 __attribute__((ext_vector_type(8)));
typedef _Float16 f16x4 __attribute__((ext_vector_type(4)));
typedef __bf16  bf16x8 __attribute__((ext_vector_type(8)));
typedef __bf16  bf16x4 __attribute__((ext_vector_type(4)));
typedef float   f32x4  __attribute__((ext_vector_type(4)));

typedef __attribute__((address_space(1))) void gv_t;
typedef __attribute__((address_space(3))) void lv_t;

__device__ __forceinline__ void gl_lds16(const void* g, void* l) {
    __builtin_amdgcn_global_load_lds((gv_t*)g, (lv_t*)l, 16, 0, 0);
}

// ---------------------------------------------------------------------------
// prep: tokens->fp16, W->wT fp16 + wT bf16 hi/lo, zero accumulators+counters
// ---------------------------------------------------------------------------
__global__ __launch_bounds__(256)
void prep(const float* __restrict__ tokens, const float* __restrict__ W,
          _Float16* __restrict__ t_h, _Float16* __restrict__ wT_h,
          __bf16* __restrict__ wT_hi, __bf16* __restrict__ wT_lo,
          float* __restrict__ zbase, float* __restrict__ aux_out)
{
    const int bid = blockIdx.x, tid = threadIdx.x;
    if (bid < 8192) {
        const size_t base = (size_t)bid * 4096 + tid * 4;
        #pragma unroll
        for (int r = 0; r < 4; ++r) {
            size_t idx = base + (size_t)r * 1024;
            float4 v = *(const float4*)&tokens[idx];
            f16x4 h;
            h[0] = (_Float16)v.x; h[1] = (_Float16)v.y;
            h[2] = (_Float16)v.z; h[3] = (_Float16)v.w;
            *(f16x4*)&t_h[idx] = h;
        }
    } else if (bid < 10240) {
        __shared__ float lw[32 * 33];
        const int local = bid - 8192;
        const int k0 = (local & 31) * 32;
        const int n0 = (local >> 5) * 32;
        {
            const int lk = tid >> 3, ln4 = (tid & 7) * 4;
            float4 v = *(const float4*)&W[(size_t)(k0 + lk) * 2048 + n0 + ln4];
            lw[(ln4 + 0) * 33 + lk] = v.x;
            lw[(ln4 + 1) * 33 + lk] = v.y;
            lw[(ln4 + 2) * 33 + lk] = v.z;
            lw[(ln4 + 3) * 33 + lk] = v.w;
        }
        __syncthreads();
        {
            const int ln = tid >> 3, lk4 = (tid & 7) * 4;
            f16x4 h; bf16x4 bh, bl;
            #pragma unroll
            for (int j = 0; j < 4; ++j) {
                float v = lw[ln * 33 + lk4 + j];
                h[j] = (_Float16)v;
                __bf16 b = (__bf16)v;
                bh[j] = b;
                bl[j] = (__bf16)(v - (float)b);
            }
            size_t o = (size_t)(n0 + ln) * 1024 + k0 + lk4;
            *(f16x4*)&wT_h[o]   = h;
            *(bf16x4*)&wT_hi[o] = bh;
            *(bf16x4*)&wT_lo[o] = bl;
        }
    } else {
        const int zb = bid - 10240;                // 0..96
        const int i = zb * 1024 + tid * 4;
        if (i < 98308)
            *(float4*)&zbase[i] = make_float4(0.f, 0.f, 0.f, 0.f);
        if (zb == 0 && tid == 0) *aux_out = 0.f;
    }
}

// ---------------------------------------------------------------------------
// main GEMM: fp16, tile 256 rows x (128 q-cols + 128 k-cols), 512 threads
// [R13 verbatim] grid 1024, 8 waves, A 3x16KB prefetch-2, B 2x16KB
// prefetch-1, vmcnt(2) + 1 barrier. Ck overlay [256][130] = 133120 B.
// ---------------------------------------------------------------------------
__global__ __launch_bounds__(512, 2)
void gemm_cos_f16(const _Float16* __restrict__ t_h, const _Float16* __restrict__ wT_h,
                  float* __restrict__ dotw, float* __restrict__ qn2w,
                  float* __restrict__ ksn2w,
                  float* __restrict__ qrow, float* __restrict__ krow)
{
    __shared__ float smem[33280];       // 133120 B (Ck overlay size)
    float* Ck = smem;                   // [256][130]

    const int bx = blockIdx.x;          // 0..1023
    const int tile_n = (bx >> 3) & 7;
    const int tile_m = ((bx >> 6) & 15) + ((bx & 7) << 4);   // 0..127
    const int m0 = tile_m * 256;
    const int n0 = tile_n * 128;
    const int tid  = threadIdx.x;       // 0..511
    const int w    = tid >> 6;          // 0..7
    const int lane = tid & 63;
    const int quad = lane >> 4;
    const int lc   = lane & 15;

    const int wm  = (w & 3) * 64;       // row quarter (0/64/128/192)
    const int wq0 = (w >> 2) * 64;      // col half (0/64) within 128

    const int st_ch = ((lane & 3) ^ ((lane >> 3) & 3)) * 8;
    const int ia0 = w * 2, ia1 = w * 2 + 1;
    const size_t a_g0 = (size_t)(m0 + ia0 * 16 + (lane >> 2)) * 1024 + st_ch;
    const size_t a_g1 = a_g0 + (size_t)16 * 1024;
    size_t b_g[2];
    #pragma unroll
    for (int j = 0; j < 2; ++j) {
        const int br = (w * 2 + j) * 16 + (lane >> 2);
        const int gr = (br < 128) ? (n0 + br) : (896 + n0 + br);
        b_g[j] = (size_t)gr * 1024 + st_ch;
    }

    char* const sb  = (char*)smem;      // A bufs: 0 / 16384 / 32768
    char* const sbB = sb + 49152;       // B bufs: 49152 / 65536 (16KB each)
    const int fr_ch = (quad ^ ((lc >> 1) & 3)) * 8;

    f32x4 accq[4][4] = {};
    f32x4 acck[4][4] = {};

#define STAGE_A(KK, BASE)                                                    \
    {                                                                        \
        const size_t kb = (size_t)(KK) * 32;                                 \
        gl_lds16(t_h + a_g0 + kb, (BASE) + ia0 * 1024);                      \
        gl_lds16(t_h + a_g1 + kb, (BASE) + ia1 * 1024);                      \
    }
#define STAGE_B(KK, BASE)                                                    \
    {                                                                        \
        const size_t kb = (size_t)(KK) * 32;                                 \
        gl_lds16(wT_h + b_g[0] + kb, (BASE) + (w * 2 + 0) * 1024);           \
        gl_lds16(wT_h + b_g[1] + kb, (BASE) + (w * 2 + 1) * 1024);           \
    }

    // prologue (issue order defines vm queue): A(0), B(0), A(1)
    STAGE_A(0, sb)
    STAGE_B(0, sbB)
    STAGE_A(1, sb + 16384)

    int acur = 0;
    int apre = 2;
    for (int kk = 0; kk < 32; ++kk) {
        if (kk < 31) {
            asm volatile("s_waitcnt vmcnt(2)" ::: "memory");
        } else {
            asm volatile("s_waitcnt vmcnt(0)" ::: "memory");
        }
        __builtin_amdgcn_s_barrier();
        if (kk < 31) STAGE_B(kk + 1, sbB + ((kk + 1) & 1) * 16384)
        if (kk < 30) STAGE_A(kk + 2, sb + apre * 16384)

        const _Float16* As = (const _Float16*)(sb + acur * 16384);
        const _Float16* Bs = (const _Float16*)(sbB + (kk & 1) * 16384);

        f16x8 af[4], bq[4], bk[4];
        #pragma unroll
        for (int mi = 0; mi < 4; ++mi)
            af[mi] = *(const f16x8*)(As + (wm + mi * 16 + lc) * 32 + fr_ch);
        #pragma unroll
        for (int ni = 0; ni < 4; ++ni) {
            bq[ni] = *(const f16x8*)(Bs + (wq0 + ni * 16 + lc) * 32 + fr_ch);
            bk[ni] = *(const f16x8*)(Bs + (128 + wq0 + ni * 16 + lc) * 32 + fr_ch);
        }
        #pragma unroll
        for (int mi = 0; mi < 4; ++mi) {
            #pragma unroll
            for (int ni = 0; ni < 4; ++ni) {
                accq[mi][ni] = __builtin_amdgcn_mfma_f32_16x16x32_f16(
                    af[mi], bq[ni], accq[mi][ni], 0, 0, 0);
                acck[mi][ni] = __builtin_amdgcn_mfma_f32_16x16x32_f16(
                    af[mi], bk[ni], acck[mi][ni], 0, 0, 0);
            }
        }
        acur = (acur == 2) ? 0 : acur + 1;
        apre = (apre == 2) ? 0 : apre + 1;
    }
#undef STAGE_A
#undef STAGE_B
    __syncthreads();   // all staging settled before the Ck overlay

    // ---- epilogue (rows 0..255, Ck stride 130) ----
    #pragma unroll
    for (int mi = 0; mi < 4; ++mi) {
        #pragma unroll
        for (int reg = 0; reg < 4; ++reg) {
            const int row = wm + mi * 16 + quad * 4 + reg;   // 0..255
            float s = 0.f, s2 = 0.f;
            #pragma unroll
            for (int ni = 0; ni < 4; ++ni) {
                s  += accq[mi][ni][reg] * accq[mi][ni][reg];
                s2 += acck[mi][ni][reg] * acck[mi][ni][reg];
            }
            s += __shfl_xor(s, 1); s += __shfl_xor(s, 2);
            s += __shfl_xor(s, 4); s += __shfl_xor(s, 8);
            if (lc == 0) atomicAdd(&qn2w[m0 + row], s);

            s2 += __shfl_xor(s2, 1); s2 += __shfl_xor(s2, 2);
            s2 += __shfl_xor(s2, 4); s2 += __shfl_xor(s2, 8);
            if (lc == 0 && row < 255) atomicAdd(&ksn2w[m0 + row + 1], s2);
        }
    }

    #pragma unroll
    for (int mi = 0; mi < 4; ++mi)
        #pragma unroll
        for (int ni = 0; ni < 4; ++ni)
            #pragma unroll
            for (int reg = 0; reg < 4; ++reg)
                Ck[(wm + mi * 16 + quad * 4 + reg) * 130 + wq0 + ni * 16 + lc] =
                    acck[mi][ni][reg];
    __syncthreads();

    #pragma unroll
    for (int mi = 0; mi < 4; ++mi) {
        #pragma unroll
        for (int reg = 0; reg < 4; ++reg) {
            const int row = wm + mi * 16 + quad * 4 + reg;
            float d = 0.f;
            if (row >= 1) {
                #pragma unroll
                for (int ni = 0; ni < 4; ++ni)
                    d += accq[mi][ni][reg]
                       * Ck[(row - 1) * 130 + wq0 + ni * 16 + lc];
            }
            d += __shfl_xor(d, 1); d += __shfl_xor(d, 2);
            d += __shfl_xor(d, 4); d += __shfl_xor(d, 8);
            if (lc == 0 && row >= 1) atomicAdd(&dotw[m0 + row], d);
        }
    }

    // boundary rows for probs_fused (128-row tiles)
    if (wm == 0 && quad == 0) {
        #pragma unroll
        for (int ni = 0; ni < 4; ++ni)
            qrow[(size_t)(tile_m * 2) * D_ + n0 + wq0 + ni * 16 + lc] =
                accq[0][ni][0];
    }
    if (wm == 128 && quad == 0) {
        #pragma unroll
        for (int ni = 0; ni < 4; ++ni)
            qrow[(size_t)(tile_m * 2 + 1) * D_ + n0 + wq0 + ni * 16 + lc] =
                accq[0][ni][0];
    }
    if (wm == 64 && quad == 3) {
        #pragma unroll
        for (int ni = 0; ni < 4; ++ni)
            krow[(size_t)(tile_m * 2) * D_ + n0 + wq0 + ni * 16 + lc] =
                acck[3][ni][3];
    }
    if (wm == 192 && quad == 3) {
        #pragma unroll
        for (int ni = 0; ni < 4; ++ni)
            krow[(size_t)(tile_m * 2 + 1) * D_ + n0 + wq0 + ni * 16 + lc] =
                acck[3][ni][3];
    }
}

// ---------------------------------------------------------------------------
// fused: boundary dot (t ≡ 0 mod 128) + probs + suspect list (|cos| < 1e-3)
// ---------------------------------------------------------------------------
__global__ __launch_bounds__(256)
void probs_fused(const float* __restrict__ qrow, const float* __restrict__ krow,
                 const float* __restrict__ start_key,
                 const float* __restrict__ dotw, const float* __restrict__ qn2w,
                 const float* __restrict__ ksn2w, float* __restrict__ probsw,
                 int* __restrict__ scount, int* __restrict__ slist)
{
    const int tile = blockIdx.x;
    const int tid = threadIdx.x;
    __shared__ float sd[4], sk[4];

    {
        const float* q  = qrow + (size_t)tile * D_;
        const float* ks = ((tile & 31) == 0) ? start_key
                                             : (krow + (size_t)(tile - 1) * D_);
        float4 qv = *(const float4*)&q[tid * 4];
        float4 kv = *(const float4*)&ks[tid * 4];
        float d  = qv.x * kv.x + qv.y * kv.y + qv.z * kv.z + qv.w * kv.w;
        float k2 = kv.x * kv.x + kv.y * kv.y + kv.z * kv.z + kv.w * kv.w;
        #pragma unroll
        for (int off = 32; off; off >>= 1) {
            d  += __shfl_down(d, off, 64);
            k2 += __shfl_down(k2, off, 64);
        }
        const int lane = tid & 63, wid = tid >> 6;
        if (lane == 0) { sd[wid] = d; sk[wid] = k2; }
    }
    __syncthreads();

    if (tid < BM) {
        const int m = tile * BM + tid;
        float dd = dotw[m], kk = ksn2w[m];
        if (tid == 0) {
            dd = sd[0] + sd[1] + sd[2] + sd[3];
            kk = sk[0] + sk[1] + sk[2] + sk[3];
        }
        float qn = fmaxf(sqrtf(qn2w[m]), 1e-8f);
        float kn = fmaxf(sqrtf(kk), 1e-8f);
        float c = dd / (qn * kn);
        probsw[m] = 0.5f * (1.f - c);
        if (fabsf(c) < 1e-3f) {
            int i = atomicAdd(scount, 1);
            if (i < SUS_CAP) slist[i] = m;
        }
    }
}

// ---------------------------------------------------------------------------
// stage-2 operand build: gather suspect rows (and predecessors) -> bf16 hi/lo
// ---------------------------------------------------------------------------
__global__ __launch_bounds__(256)
void gather_split(const float* __restrict__ tokens, const int* __restrict__ scount,
                  const int* __restrict__ slist,
                  __bf16* __restrict__ As_hi, __bf16* __restrict__ As_lo)
{
    int n = *scount; if (n > SUS_CAP) n = SUS_CAP;
    const int n_up = (n + 127) & ~127;
    const int slot = blockIdx.x;
    const int sl = slot & 2047;
    if (sl >= n_up) return;
    const int tid = threadIdx.x;

    int src = -1;
    if (sl < n) {
        int t = slist[sl];
        if (slot < 2048) src = t;
        else src = ((t & 4095) == 0) ? t : (t - 1);
    }
    bf16x4 h = {}, l = {};
    if (src >= 0) {
        float4 v = *(const float4*)&tokens[(size_t)src * 1024 + tid * 4];
        float vs[4] = {v.x, v.y, v.z, v.w};
        #pragma unroll
        for (int j = 0; j < 4; ++j) {
            __bf16 b = (__bf16)vs[j];
            h[j] = b;
            l[j] = (__bf16)(vs[j] - (float)b);
        }
    }
    size_t o = (size_t)slot * 1024 + tid * 4;
    *(bf16x4*)&As_hi[o] = h;
    *(bf16x4*)&As_lo[o] = l;
}

// ---------------------------------------------------------------------------
// stage-2 GEMM: bf16, K-SPLIT over the 3 slabs (R15).
// grid (8, 32, 3): z = slab; slab 0: As_hi*wT_hi -> C2a, slab 1:
// As_hi*wT_lo -> C2b, slab 2: As_lo*wT_hi -> C2c. Each block: R13's
// 3x16KB prefetch-2 vmcnt(4) loop, 32 iters. dot_fix sums the slabs.
// suspect blocks (tm<16): q-cols only; predecessor blocks: k-cols only.
// ---------------------------------------------------------------------------
__global__ __launch_bounds__(256, 2)
void gemm2(const __bf16* __restrict__ As_hi, const __bf16* __restrict__ As_lo,
           const __bf16* __restrict__ wT_hi, const __bf16* __restrict__ wT_lo,
           const int* __restrict__ scount, float* __restrict__ outb)
{
    int n = *scount; if (n > SUS_CAP) n = SUS_CAP;
    const int tm = blockIdx.y;
    const int local_base = (tm < 16) ? tm * 128 : (tm - 16) * 128;
    if (local_base >= n) return;
    const int m0 = (tm < 16) ? tm * 128 : 2048 + (tm - 16) * 128;

    const int slab = blockIdx.z;        // 0..2
    const __bf16* Ap = (slab == 2) ? As_lo : As_hi;
    const __bf16* Bp = (slab == 1) ? wT_lo : wT_hi;
    float* C2 = outb + ((slab == 0) ? C2A_OFF : (slab == 1) ? C2B_OFF : C2C_OFF);

    __shared__ float smem[12288];       // 49152 B = 3 staging bufs x 16 KB

    const int tile_n = blockIdx.x;      // 0..7
    const int n0 = tile_n * 128;
    const int colbase = ((tm < 16) ? 0 : 1024) + n0;
    const int tid  = threadIdx.x;
    const int w    = tid >> 6;
    const int lane = tid & 63;
    const int quad = lane >> 4;
    const int lc   = lane & 15;
    const int wm  = (w & 1) * 64;
    const int wq0 = (w >> 1) * 32;

    const int ia0 = w * 2, ia1 = w * 2 + 1;
    const int st_ch = ((lane & 3) ^ ((lane >> 3) & 3)) * 8;
    const size_t a_g0 = (size_t)(m0 + ia0 * 16 + (lane >> 2)) * 1024 + st_ch;
    const size_t a_g1 = a_g0 + (size_t)16 * 1024;
    const int br0 = ia0 * 16 + (lane >> 2);
    const int br1 = br0 + 16;
    const size_t b_g0 = (size_t)(colbase + br0) * 1024 + st_ch;
    const size_t b_g1 = (size_t)(colbase + br1) * 1024 + st_ch;

    char* const sb = (char*)smem;
    const int fr_ch = (quad ^ ((lc >> 1) & 3)) * 8;

    f32x4 accq[4][2] = {};
    f32x4 acck[4][2] = {};

    // prologue: kk=0 -> buf0, kk=1 -> buf1
    gl_lds16(Ap + a_g0,      sb + ia0 * 1024);
    gl_lds16(Ap + a_g1,      sb + ia1 * 1024);
    gl_lds16(Bp + b_g0,      sb + 8192 + ia0 * 1024);
    gl_lds16(Bp + b_g1,      sb + 8192 + ia1 * 1024);
    gl_lds16(Ap + a_g0 + 32, sb + 16384 + ia0 * 1024);
    gl_lds16(Ap + a_g1 + 32, sb + 16384 + ia1 * 1024);
    gl_lds16(Bp + b_g0 + 32, sb + 16384 + 8192 + ia0 * 1024);
    gl_lds16(Bp + b_g1 + 32, sb + 16384 + 8192 + ia1 * 1024);

    int cur = 0;
    for (int kk = 0; kk < 32; ++kk) {
        if (kk < 31) {
            asm volatile("s_waitcnt vmcnt(4)" ::: "memory");
        } else {
            asm volatile("s_waitcnt vmcnt(0)" ::: "memory");
        }
        __builtin_amdgcn_s_barrier();
        if (kk < 30) {
            const size_t kb2 = (size_t)(kk + 2) * 32;
            int nxt = cur + 2; if (nxt >= 3) nxt -= 3;
            char* nb = sb + nxt * 16384;
            gl_lds16(Ap + a_g0 + kb2, nb + ia0 * 1024);
            gl_lds16(Ap + a_g1 + kb2, nb + ia1 * 1024);
            gl_lds16(Bp + b_g0 + kb2, nb + 8192 + ia0 * 1024);
            gl_lds16(Bp + b_g1 + kb2, nb + 8192 + ia1 * 1024);
        }
        const __bf16* As = (const __bf16*)(sb + cur * 16384);
        const __bf16* Bs = As + 4096;

        bf16x8 af[4], bq[2], bk[2];
        #pragma unroll
        for (int mi = 0; mi < 4; ++mi)
            af[mi] = *(const bf16x8*)(As + (wm + mi * 16 + lc) * 32 + fr_ch);
        #pragma unroll
        for (int ni = 0; ni < 2; ++ni) {
            bq[ni] = *(const bf16x8*)(Bs + (wq0 + ni * 16 + lc) * 32 + fr_ch);
            bk[ni] = *(const bf16x8*)(Bs + (64 + wq0 + ni * 16 + lc) * 32 + fr_ch);
        }
        #pragma unroll
        for (int mi = 0; mi < 4; ++mi) {
            #pragma unroll
            for (int ni = 0; ni < 2; ++ni) {
                accq[mi][ni] = __builtin_amdgcn_mfma_f32_16x16x32_bf16(
                    af[mi], bq[ni], accq[mi][ni], 0, 0, 0);
                acck[mi][ni] = __builtin_amdgcn_mfma_f32_16x16x32_bf16(
                    af[mi], bk[ni], acck[mi][ni], 0, 0, 0);
            }
        }
        cur = (cur == 2) ? 0 : cur + 1;
    }

    #pragma unroll
    for (int mi = 0; mi < 4; ++mi) {
        #pragma unroll
        for (int reg = 0; reg < 4; ++reg) {
            const int row = m0 + wm + mi * 16 + quad * 4 + reg;
            #pragma unroll
            for (int ni = 0; ni < 2; ++ni) {
                C2[(size_t)row * 2048 + colbase + wq0 + ni * 16 + lc] = accq[mi][ni][reg];
                C2[(size_t)row * 2048 + colbase + 64 + wq0 + ni * 16 + lc] = acck[mi][ni][reg];
            }
        }
    }
}

// ---------------------------------------------------------------------------
// stage-2 resolve: dot/norms from C2a+C2b+C2c; sub-suspects -> slist2.
// on append, zero the suspect's 3-float fix3acc slot.
// ---------------------------------------------------------------------------
__global__ __launch_bounds__(256)
void dot_fix(const float* __restrict__ outb, const float* __restrict__ start_key,
             const int* __restrict__ scount, const int* __restrict__ slist,
             float* __restrict__ probsw, int* __restrict__ scount2,
             int* __restrict__ slist2, float* __restrict__ fix3acc)
{
    int n = *scount; if (n > SUS_CAP) n = SUS_CAP;
    const int s = blockIdx.x;
    if (s >= n) return;
    const int tid = threadIdx.x;
    const int t = slist[s];
    const bool st = (t & 4095) == 0;
    const size_t qoff = (size_t)s * 2048 + tid * 4;
    const size_t koff = (size_t)(2048 + s) * 2048 + 1024 + tid * 4;

    float4 qa = *(const float4*)&outb[C2A_OFF + qoff];
    float4 qb = *(const float4*)&outb[C2B_OFF + qoff];
    float4 qc = *(const float4*)&outb[C2C_OFF + qoff];
    float4 qv = make_float4(qa.x + qb.x + qc.x, qa.y + qb.y + qc.y,
                            qa.z + qb.z + qc.z, qa.w + qb.w + qc.w);
    float4 kv;
    if (st) {
        kv = *(const float4*)&start_key[tid * 4];
    } else {
        float4 ka = *(const float4*)&outb[C2A_OFF + koff];
        float4 kb = *(const float4*)&outb[C2B_OFF + koff];
        float4 kc = *(const float4*)&outb[C2C_OFF + koff];
        kv = make_float4(ka.x + kb.x + kc.x, ka.y + kb.y + kc.y,
                         ka.z + kb.z + kc.z, ka.w + kb.w + kc.w);
    }
    float d  = qv.x * kv.x + qv.y * kv.y + qv.z * kv.z + qv.w * kv.w;
    float q2 = qv.x * qv.x + qv.y * qv.y + qv.z * qv.z + qv.w * qv.w;
    float k2 = kv.x * kv.x + kv.y * kv.y + kv.z * kv.z + kv.w * kv.w;
    #pragma unroll
    for (int off = 32; off; off >>= 1) {
        d  += __shfl_down(d, off, 64);
        q2 += __shfl_down(q2, off, 64);
        k2 += __shfl_down(k2, off, 64);
    }
    __shared__ float sd[4], sq[4], sk[4];
    const int lane = tid & 63, wid = tid >> 6;
    if (lane == 0) { sd[wid] = d; sq[wid] = q2; sk[wid] = k2; }
    __syncthreads();
    if (tid == 0) {
        float D  = sd[0] + sd[1] + sd[2] + sd[3];
        float Q2 = sq[0] + sq[1] + sq[2] + sq[3];
        float K2 = sk[0] + sk[1] + sk[2] + sk[3];
        float c = D / (fmaxf(sqrtf(Q2), 1e-8f) * fmaxf(sqrtf(K2), 1e-8f));
        if (fabsf(c) < 1e-4f) {
            int i = atomicAdd(scount2, 1);
            if (i < SUS_CAP) {
                slist2[i] = t;
                float* fa = fix3acc + 3 * i;
                fa[0] = 0.f; fa[1] = 0.f; fa[2] = 0.f;
            }
        } else {
            probsw[t] = 0.5f * (1.f - c);
        }
    }
}

// ---------------------------------------------------------------------------
// stage-3a: exact fp32 recompute, split over OUTPUT cols.  [R10 verbatim]
// ---------------------------------------------------------------------------
__global__ __launch_bounds__(256)
void fixup3a(const float* __restrict__ tokens, const float* __restrict__ W,
             const float* __restrict__ start_key, const int* __restrict__ scount2,
             const int* __restrict__ slist2, float* __restrict__ fix3acc)
{
    __shared__ float ta[1024], tb[1024], kvs[128];
    const int tid = threadIdx.x;
    const int lane = tid & 63;
    const int c = blockIdx.x & 7;
    int n = *scount2; if (n > SUS_CAP) n = SUS_CAP;

    for (int i = blockIdx.x >> 3; i < n; i += 128) {
        const int t = slist2[i];
        const bool st = (t & 4095) == 0;
        *(float4*)&ta[tid * 4] = *(const float4*)&tokens[(size_t)t * 1024 + tid * 4];
        if (!st)
            *(float4*)&tb[tid * 4] = *(const float4*)&tokens[(size_t)(t - 1) * 1024 + tid * 4];
        __syncthreads();

        float qd = 0.f, q2p = 0.f, k2p = 0.f, dotp = 0.f;
        if (tid < 128) {
            const float* Wp = W + c * 128 + tid;
            float a0 = 0.f, a1 = 0.f, a2 = 0.f, a3 = 0.f;
            for (int k = 0; k < 1024; k += 4) {
                a0 = fmaf(ta[k + 0], Wp[(size_t)(k + 0) * 2048], a0);
                a1 = fmaf(ta[k + 1], Wp[(size_t)(k + 1) * 2048], a1);
                a2 = fmaf(ta[k + 2], Wp[(size_t)(k + 2) * 2048], a2);
                a3 = fmaf(ta[k + 3], Wp[(size_t)(k + 3) * 2048], a3);
            }
            qd = (a0 + a1) + (a2 + a3);
            q2p = qd * qd;
        } else {
            const int j = tid - 128;
            float kd;
            if (st) {
                kd = start_key[c * 128 + j];
            } else {
                const float* Wp = W + 1024 + c * 128 + j;
                float a0 = 0.f, a1 = 0.f, a2 = 0.f, a3 = 0.f;
                for (int k = 0; k < 1024; k += 4) {
                    a0 = fmaf(tb[k + 0], Wp[(size_t)(k + 0) * 2048], a0);
                    a1 = fmaf(tb[k + 1], Wp[(size_t)(k + 1) * 2048], a1);
                    a2 = fmaf(tb[k + 2], Wp[(size_t)(k + 2) * 2048], a2);
                    a3 = fmaf(tb[k + 3], Wp[(size_t)(k + 3) * 2048], a3);
                }
                kd = (a0 + a1) + (a2 + a3);
            }
            kvs[j] = kd;
            k2p = kd * kd;
        }
        __syncthreads();
        if (tid < 128) dotp = qd * kvs[tid];

        #pragma unroll
        for (int off = 32; off; off >>= 1) {
            dotp += __shfl_down(dotp, off, 64);
            q2p  += __shfl_down(q2p,  off, 64);
            k2p  += __shfl_down(k2p,  off, 64);
        }
        if (lane == 0) {
            float* fa = fix3acc + 3 * i;
            atomicAdd(&fa[0], dotp);
            atomicAdd(&fa[1], q2p);
            atomicAdd(&fa[2], k2p);
        }
        __syncthreads();   // protect ta/tb/kvs before next iteration
    }
}

// ---------------------------------------------------------------------------
// stage-3b: finish probs from accumulated {dot, q2, k2}
// ---------------------------------------------------------------------------
__global__ __launch_bounds__(256)
void fixup3b(const int* __restrict__ scount2, const int* __restrict__ slist2,
             const float* __restrict__ fix3acc, float* __restrict__ probsw)
{
    int n = *scount2; if (n > SUS_CAP) n = SUS_CAP;
    for (int i = threadIdx.x + blockIdx.x * 256; i < n; i += 256 * gridDim.x) {
        const int t = slist2[i];
        const float* fa = fix3acc + 3 * i;
        float D = fa[0], Q2 = fa[1], K2 = fa[2];
        float qn = fmaxf(sqrtf(Q2), 1e-8f), kn = fmaxf(sqrtf(K2), 1e-8f);
        probsw[t] = 0.5f * (1.f - D / (qn * kn));
    }
}

// ---------------------------------------------------------------------------
__global__ __launch_bounds__(1024)
void chunk_scan_p(const float* __restrict__ probsw, int* __restrict__ bposw,
                  int* __restrict__ ncw, float* __restrict__ aux_out,
                  float* __restrict__ out_lens)
{
    const int b = blockIdx.x, tid = threadIdx.x;
    const int lane = tid & 63, wid = tid >> 6;
    __shared__ int wcnt[16];
    __shared__ float wsum[16];
    __shared__ int s_nc;
    __shared__ float s_ps;

    const int base = b * L_ + tid * 4;
    float4 pv = *(const float4*)&probsw[base];
    const float p[4] = {pv.x, pv.y, pv.z, pv.w};

    bool mk[4]; int cnt = 0; float psum = 0.f;
    #pragma unroll
    for (int j = 0; j < 4; ++j) {
        mk[j] = (p[j] > 0.5f) || ((tid * 4 + j) == 0);
        cnt += mk[j] ? 1 : 0;
        psum += p[j];
    }
    int inc = cnt;
    #pragma unroll
    for (int off = 1; off < 64; off <<= 1) {
        int nn = __shfl_up(inc, off, 64);
        if (lane >= off) inc += nn;
    }
    float ps = psum;
    #pragma unroll
    for (int off = 32; off; off >>= 1) ps += __shfl_down(ps, off, 64);
    if (lane == 63) wcnt[wid] = inc;
    if (lane == 0)  wsum[wid] = ps;
    __syncthreads();
    if (tid == 0) {
        int run = 0; float tt = 0.f;
        for (int i = 0; i < 16; ++i) { int c = wcnt[i]; wcnt[i] = run; run += c; tt += wsum[i]; }
        s_nc = run; s_ps = tt;
    }
    __syncthreads();
    const int nc = s_nc;
    int idx = wcnt[wid] + (inc - cnt);
    #pragma unroll
    for (int j = 0; j < 4; ++j)
        if (mk[j]) { bposw[b * L_ + idx] = tid * 4 + j; ++idx; }
    if (tid == 0) {
        ncw[b] = nc;
        float G  = s_ps * (1.f / L_);
        float Fm = (float)nc * (1.f / L_);
        atomicAdd(aux_out, 0.0045f * (5.f * Fm * G + (1.f - Fm) * (1.f - G)));
    }
    __syncthreads();
    #pragma unroll
    for (int j = 0; j < 4; ++j) {
        int i = tid * 4 + j;
        float len = 0.f;
        if (i < nc) {
            int pi  = bposw[b * L_ + i];
            int nxt = (i + 1 < nc) ? bposw[b * L_ + i + 1] : L_;
            len = (float)(nxt - pi);
        }
        out_lens[b * L_ + i] = len;
    }
}

__global__ __launch_bounds__(256)
void gather_ds(const float* __restrict__ tokens, const float* __restrict__ probsw,
               const int* __restrict__ bposw, const int* __restrict__ ncw,
               float* __restrict__ out)
{
    const int row = blockIdx.x;
    const int b = row >> 12, i = row & 4095;
    const int nc = ncw[b];
    float4 v = make_float4(0.f, 0.f, 0.f, 0.f);
    if (i < nc) {
        const int t = bposw[b * L_ + i];
        const float pv = probsw[b * L_ + t];
        float4 tv = *(const float4*)&tokens[((size_t)(b << 12) + t) * D_ + threadIdx.x * 4];
        v = make_float4(tv.x * pv, tv.y * pv, tv.z * pv, tv.w * pv);
    }
    *(float4*)&out[(size_t)row * D_ + threadIdx.x * 4] = v;
}

// ===========================================================================
extern "C" void kernel_launch(void* const* d_in, const int* in_sizes, int n_in,
                              void* d_out, int out_size, void* d_ws, size_t ws_size,
                              hipStream_t stream)
{
    const float* tokens    = (const float*)d_in[0];
    const float* W_qk      = (const float*)d_in[1];
    const float* start_key = (const float*)d_in[2];
    float* out = (float*)d_out;
    float* lens_out = out + DS_ELEMS;
    float* aux_out  = out + DS_ELEMS + M_TOT;

    // ws layout (floats) — total 1740812 floats ≈ 6.96 MB
    float* wf = (float*)d_ws;
    float* dotw    = wf;                       // 32768
    float* qn2w    = wf + 32768;               // 32768
    float* ksn2w   = wf + 65536;               // 32768
    int*   scount  = (int*)(wf + 98304);       // 1
    int*   scount2 = (int*)(wf + 98305);       // 1 (+2 pad)
    float* probsw  = wf + 98308;               // 32768
    int*   bposw   = (int*)(wf + 131076);      // 32768
    int*   ncw     = (int*)(wf + 163844);      // 8
    int*   slist   = (int*)(wf + 163852);      // 2048
    int*   slist2  = (int*)(wf + 165900);      // 2048
    float* qrow    = wf + 167948;              // 262144
    float* krow    = wf + 430092;              // 262144
    _Float16* wT_h = (_Float16*)(wf + 692236); // 2097152 halves

    // d_out scratch (overwritten by gather_ds at the end)
    _Float16* t_h  = (_Float16*)out;                   // [0, 64MB): dead after gemm_cos
    __bf16* As_hi  = (__bf16*)(out + 16777216);        // 4096x1024
    __bf16* As_lo  = (__bf16*)(out + 18874368);
    // C2a = out + 20971520 (32MB); C2b = out + 0; C2c = out + 8388608
    __bf16* wT_hi  = (__bf16*)(out + 29360128);        // 2048x1024
    __bf16* wT_lo  = (__bf16*)(out + 30408704);
    // fix3acc: 3 floats x SUS_CAP, reuses the As_lo region (dead after gemm2,
    // zeroed per-slot by dot_fix, consumed by fixup3a/b before gather_ds).
    float* fix3acc = out + 18874368;

    prep<<<10337, 256, 0, stream>>>(tokens, W_qk, t_h, wT_h, wT_hi, wT_lo,
                                    wf, aux_out);
    gemm_cos_f16<<<1024, 512, 0, stream>>>(t_h, wT_h, dotw, qn2w, ksn2w,
                                           qrow, krow);
    probs_fused<<<256, 256, 0, stream>>>(qrow, krow, start_key, dotw, qn2w,
                                         ksn2w, probsw, scount, slist);
    gather_split<<<4096, 256, 0, stream>>>(tokens, scount, slist, As_hi, As_lo);
    gemm2<<<dim3(8, 32, 3), 256, 0, stream>>>(As_hi, As_lo, wT_hi, wT_lo,
                                              scount, out);
    dot_fix<<<2048, 256, 0, stream>>>(out, start_key, scount, slist, probsw,
                                      scount2, slist2, fix3acc);
    fixup3a<<<1024, 256, 0, stream>>>(tokens, W_qk, start_key, scount2, slist2,
                                      fix3acc);
    fixup3b<<<32, 256, 0, stream>>>(scount2, slist2, fix3acc, probsw);
    chunk_scan_p<<<B_, 1024, 0, stream>>>(probsw, bposw, ncw, aux_out, lens_out);
    gather_ds<<<M_TOT, 256, 0, stream>>>(tokens, probsw, bposw, ncw, out);
}